// Round 17
// baseline (260.716 us; speedup 1.0000x reference)
//
#include <hip/hip_runtime.h>

#define DD    48
#define SP    (48*48*48)      // 110592 voxels
#define CIN   16
#define COUT  32
#define KK    9
#define NG    8               // groupnorm groups
#define EPSV  1e-5f

// ---------------------------------------------------------------------------
// Kernel 0: transpose x [ci][v] -> xt [v][ci] (one voxel's 16 ci = 64B line).
// Block 0 also zeros the padded stats buffer.
// ---------------------------------------------------------------------------
__global__ __launch_bounds__(256) void k_xt(const float* __restrict__ x,
                                            float* __restrict__ xt,
                                            float* __restrict__ stats) {
    int t = threadIdx.x;
    int vb = t >> 2, c = t & 3;
    int v = blockIdx.x * 64 + vb;
    float4 o;
    o.x = x[(4 * c + 0) * SP + v];
    o.y = x[(4 * c + 1) * SP + v];
    o.z = x[(4 * c + 2) * SP + v];
    o.w = x[(4 * c + 3) * SP + v];
    *reinterpret_cast<float4*>(xt + v * 16 + 4 * c) = o;
    if (blockIdx.x == 0) stats[t] = 0.0f;
}

// ---------------------------------------------------------------------------
// Kernel 1: offset conv 3x3x3 (16->18) + BN(eval) + tanh, V=2 voxels/thread.
// Thread (vq,c) handles voxels v0=bid*128+vq*2, v1=v0+1 (same d,w; h,h+1).
// One weight ds_read serves BOTH voxels (halves per-voxel LDS-instr count —
// R16 diagnosis: 486 ds_read/thread was ~66us of LDS issue). Adjacent-h also
// shares conv columns: load 4 cols/(kd,kw), kh-window them for both voxels.
// off layout: [ch][v]  (ch 0..8 = z-offsets, 9..17 = y-offsets)
// ---------------------------------------------------------------------------
__global__ __launch_bounds__(256) void k_off18(
    const float* __restrict__ xt,  const float* __restrict__ ow,
    const float* __restrict__ ob,  const float* __restrict__ bng,
    const float* __restrict__ bnb, const float* __restrict__ bnm,
    const float* __restrict__ bnv, float* __restrict__ off)
{
    __shared__ float cw[27 * 4 * 72];    // [tap][c][ch18][ci4], 31104 B
    __shared__ float bnsc[18], bnsh[18];

    for (int i = threadIdx.x; i < 27 * CIN * 18; i += 256) {
        int ch = i % 18; int r = i / 18; int ci = r % CIN; int tap = r / CIN;
        int c = ci >> 2, j = ci & 3;
        cw[(tap * 4 + c) * 72 + ch * 4 + j] = ow[(ch * CIN + ci) * 27 + tap];
    }
    if (threadIdx.x < 18) {
        int ch = threadIdx.x;
        float sc = bng[ch] * rsqrtf(bnv[ch] + EPSV);
        bnsc[ch] = sc;
        bnsh[ch] = (ob[ch] - bnm[ch]) * sc + bnb[ch];
    }
    __syncthreads();

    // XCD-aware swizzle (864 % 8 == 0 -> bijective)
    const int nwg = SP / 128;                // 864
    int bid = (int)blockIdx.x;
    bid = (bid & 7) * (nwg >> 3) + (bid >> 3);

    const int t  = threadIdx.x;
    const int c  = t & 3;
    const int vq = t >> 2;                   // 0..63
    const int v0 = bid * 128 + vq * 2;       // even -> h0 even <= 46
    const int h0 = v0 % DD;
    const int w  = (v0 / DD) % DD;
    const int d  = v0 / (DD * DD);

    const float* xc = xt + 4 * c;

    float a0[18], a1[18];
#pragma unroll
    for (int ch = 0; ch < 18; ++ch) { a0[ch] = 0.0f; a1[ch] = 0.0f; }

#pragma unroll
    for (int kd = 0; kd < 3; ++kd) {
        int z = d + kd - 1; bool okz = (unsigned)z < (unsigned)DD;
#pragma unroll
        for (int kw = 0; kw < 3; ++kw) {
            int yy = w + kw - 1;
            if (okz && (unsigned)yy < (unsigned)DD) {
                const float* row = xc + ((z * DD + yy) * DD) * 16;
                float4 xv[4];                  // cols h0-1 .. h0+2
#pragma unroll
                for (int j = 0; j < 4; ++j) {
                    int col = h0 - 1 + j;
                    float4 val = make_float4(0.f, 0.f, 0.f, 0.f);
                    if ((unsigned)col < (unsigned)DD)
                        val = *reinterpret_cast<const float4*>(row + col * 16);
                    xv[j] = val;
                }
#pragma unroll
                for (int kh = 0; kh < 3; ++kh) {
                    int tap = (kd * 3 + kw) * 3 + kh;
                    const float4* wrow = reinterpret_cast<const float4*>(
                        &cw[(tap * 4 + c) * 72]);
#pragma unroll
                    for (int ch = 0; ch < 18; ++ch) {
                        float4 w4 = wrow[ch];
                        a0[ch] += w4.x * xv[kh].x + w4.y * xv[kh].y
                                + w4.z * xv[kh].z + w4.w * xv[kh].w;
                        a1[ch] += w4.x * xv[kh+1].x + w4.y * xv[kh+1].y
                                + w4.z * xv[kh+1].z + w4.w * xv[kh+1].w;
                    }
                }
            }
        }
    }

#pragma unroll
    for (int ch = 0; ch < 18; ++ch) {
        a0[ch] += __shfl_xor(a0[ch], 1);
        a0[ch] += __shfl_xor(a0[ch], 2);
        a0[ch] = tanhf(a0[ch] * bnsc[ch] + bnsh[ch]);
        a1[ch] += __shfl_xor(a1[ch], 1);
        a1[ch] += __shfl_xor(a1[ch], 2);
        a1[ch] = tanhf(a1[ch] * bnsc[ch] + bnsh[ch]);
    }

    // static-index write arms; float2 covers the voxel pair (coalesced)
#pragma unroll
    for (int cc = 0; cc < 4; ++cc) {
        if (c == cc) {
#pragma unroll
            for (int j = 0; j < 4; ++j) {
                int ch = cc * 4 + j;
                *reinterpret_cast<float2*>(&off[ch * SP + v0]) =
                    make_float2(a0[ch], a1[ch]);
            }
        }
    }
    if (c == 0) *reinterpret_cast<float2*>(&off[16 * SP + v0]) = make_float2(a0[16], a1[16]);
    if (c == 1) *reinterpret_cast<float2*>(&off[17 * SP + v0]) = make_float2(a0[17], a1[17]);
}

// ---------------------------------------------------------------------------
// Kernel 2: snake sample + fused (1,1,K)-stride-K conv (16->32) + GN stats,
// V=2 voxels/thread (same d,w; h,h+1): one weight ds_read -> FMAs for both
// voxels (per-voxel LDS-instr halves; R16: 288 ds_read/thread = ~39us issue).
// Center-out incremental cumsum (R8 structure, no 9-tap register arrays).
// Block 128 thr = 32 vq x 4 ci-chunks x 2 vox = 64 voxels; grid 1728.
// ---------------------------------------------------------------------------
__global__ __launch_bounds__(128) void k_snake(
    const float* __restrict__ xt,  const float* __restrict__ off,
    const float* __restrict__ dw,  const float* __restrict__ db,
    float* __restrict__ pre,       float* __restrict__ stats)
{
    // wl[(k*4 + c)*132 + co*4 + j] = dw[co][ci=4c+j][k]; 19 KB
    // chunk bank offsets 0/4/8/12 -> conflict-free b128 broadcast
    __shared__ float wl[KK * 4 * 132];
    __shared__ float lstat[16];
    for (int i = threadIdx.x; i < KK * CIN * COUT; i += 128) {
        int co = i % COUT; int r = i / COUT; int ci = r % CIN; int k = r / CIN;
        int c = ci >> 2, j = ci & 3;
        wl[(k * 4 + c) * 132 + co * 4 + j] = dw[(co * CIN + ci) * KK + k];
    }
    if (threadIdx.x < 16) lstat[threadIdx.x] = 0.0f;
    __syncthreads();

    // XCD-aware swizzle (1728 % 8 == 0 -> bijective)
    const int nwg = SP / 64;                 // 1728
    int bid = (int)blockIdx.x;
    bid = (bid & 7) * (nwg >> 3) + (bid >> 3);

    const int t  = threadIdx.x;
    const int c  = t & 3;                    // ci chunk
    const int vq = t >> 2;                   // 0..31
    const int v0 = bid * 64 + vq * 2;        // even -> h0 even <= 46
    const int h0 = v0 % DD;
    const int w  = (v0 / DD) % DD;
    const int d  = v0 / (DD * DD);

    float acc0[COUT], acc1[COUT];
#pragma unroll
    for (int co = 0; co < COUT; ++co) { acc0[co] = 0.0f; acc1[co] = 0.0f; }

    const float* base = xt + 4 * c;

    // One tap for both voxels. xc0 = h0+k-4; m0=0 implies m1=0 (xc1=xc0+1),
    // so the early-out covers the both-dead case; m1 masks voxel1 at xc0==46.
    auto tap = [&](int k, float cz0, float cy0, float cz1, float cy1) {
        int xc0 = h0 + k - 4;
        if (xc0 >= DD - 1) return;               // both contributions exactly 0
        float m1 = (xc0 + 1 >= DD - 1) ? 0.0f : 1.0f;
        int a0c = max(xc0, 0);
        int a1c = max(xc0 + 1, 0);

        // voxel0 bilinear (weight 1 in x by construction)
        float zf = fminf(fmaxf((float)d + cz0, 0.0f), 47.0f);
        float yf = fminf(fmaxf((float)w + cy0, 0.0f), 47.0f);
        int z0 = (int)zf, y0 = (int)yf;
        int z1 = min(z0 + 1, 47), y1 = min(y0 + 1, 47);
        float wz1 = zf - (float)z0, wz0 = (float)z1 - zf;
        float wy1 = yf - (float)y0, wy0 = (float)y1 - yf;
        float p00 = wz0 * wy0, p01 = wz0 * wy1, p10 = wz1 * wy0, p11 = wz1 * wy1;

        // voxel1 bilinear (masked by m1)
        float zg = fminf(fmaxf((float)d + cz1, 0.0f), 47.0f);
        float yg = fminf(fmaxf((float)w + cy1, 0.0f), 47.0f);
        int u0 = (int)zg, q0 = (int)yg;
        int u1 = min(u0 + 1, 47), q1 = min(q0 + 1, 47);
        float vz1 = zg - (float)u0, vz0 = (float)u1 - zg;
        float vy1 = yg - (float)q0, vy0 = (float)q1 - yg;
        float r00 = vz0 * vy0 * m1, r01 = vz0 * vy1 * m1;
        float r10 = vz1 * vy0 * m1, r11 = vz1 * vy1 * m1;

        float4 A = *reinterpret_cast<const float4*>(base + ((z0 * DD + y0) * DD + a0c) * 16);
        float4 B = *reinterpret_cast<const float4*>(base + ((z0 * DD + y1) * DD + a0c) * 16);
        float4 C = *reinterpret_cast<const float4*>(base + ((z1 * DD + y0) * DD + a0c) * 16);
        float4 E = *reinterpret_cast<const float4*>(base + ((z1 * DD + y1) * DD + a0c) * 16);
        float s00 = p00 * A.x + p01 * B.x + p10 * C.x + p11 * E.x;
        float s01 = p00 * A.y + p01 * B.y + p10 * C.y + p11 * E.y;
        float s02 = p00 * A.z + p01 * B.z + p10 * C.z + p11 * E.z;
        float s03 = p00 * A.w + p01 * B.w + p10 * C.w + p11 * E.w;

        float4 F = *reinterpret_cast<const float4*>(base + ((u0 * DD + q0) * DD + a1c) * 16);
        float4 G = *reinterpret_cast<const float4*>(base + ((u0 * DD + q1) * DD + a1c) * 16);
        float4 H = *reinterpret_cast<const float4*>(base + ((u1 * DD + q0) * DD + a1c) * 16);
        float4 I = *reinterpret_cast<const float4*>(base + ((u1 * DD + q1) * DD + a1c) * 16);
        float s10 = r00 * F.x + r01 * G.x + r10 * H.x + r11 * I.x;
        float s11 = r00 * F.y + r01 * G.y + r10 * H.y + r11 * I.y;
        float s12 = r00 * F.z + r01 * G.z + r10 * H.z + r11 * I.z;
        float s13 = r00 * F.w + r01 * G.w + r10 * H.w + r11 * I.w;

        const float4* wrow = reinterpret_cast<const float4*>(&wl[(k * 4 + c) * 132]);
#pragma unroll
        for (int co = 0; co < COUT; ++co) {
            float4 w4 = wrow[co];                         // ONE read, TWO voxels
            acc0[co] += w4.x * s00 + w4.y * s01 + w4.z * s02 + w4.w * s03;
            acc1[co] += w4.x * s10 + w4.y * s11 + w4.z * s12 + w4.w * s13;
        }
    };

    // Walk k outward from center: incremental snake cumsum for both voxels.
    tap(4, 0.0f, 0.0f, 0.0f, 0.0f);
    {
        float rz0 = 0.0f, ry0 = 0.0f, rz1 = 0.0f, ry1 = 0.0f;
#pragma unroll
        for (int k = 3; k >= 0; --k) {
            float2 oz = *reinterpret_cast<const float2*>(&off[k * SP + v0]);
            float2 oy = *reinterpret_cast<const float2*>(&off[(KK + k) * SP + v0]);
            rz0 += oz.x; rz1 += oz.y; ry0 += oy.x; ry1 += oy.y;
            tap(k, rz0, ry0, rz1, ry1);
        }
    }
    {
        float rz0 = 0.0f, ry0 = 0.0f, rz1 = 0.0f, ry1 = 0.0f;
#pragma unroll
        for (int k = 5; k < KK; ++k) {
            float2 oz = *reinterpret_cast<const float2*>(&off[k * SP + v0]);
            float2 oy = *reinterpret_cast<const float2*>(&off[(KK + k) * SP + v0]);
            rz0 += oz.x; rz1 += oz.y; ry0 += oy.x; ry1 += oy.y;
            tap(k, rz0, ry0, rz1, ry1);
        }
    }

    // Reduce the 4 ci-chunk partials -> all lanes hold full acc for both vox
#pragma unroll
    for (int co = 0; co < COUT; ++co) {
        acc0[co] += __shfl_xor(acc0[co], 1);
        acc0[co] += __shfl_xor(acc0[co], 2);
        acc0[co] += db[co];
        acc1[co] += __shfl_xor(acc1[co], 1);
        acc1[co] += __shfl_xor(acc1[co], 2);
        acc1[co] += db[co];
    }

    // Store: lane chunk cc writes co = cc*8..cc*8+7, float2 per voxel pair
#pragma unroll
    for (int cc = 0; cc < 4; ++cc) {
        if (c == cc) {
#pragma unroll
            for (int j = 0; j < 8; ++j) {
                int co = cc * 8 + j;
                *reinterpret_cast<float2*>(&pre[co * SP + v0]) =
                    make_float2(acc0[co], acc1[co]);
            }
        }
    }

    // GN stats over both voxels; xor over lane bits 2..5 sums the 16 vq of
    // this wave's chunk-class (each voxel pair counted exactly once).
#pragma unroll
    for (int g = 0; g < NG; ++g) {
        float s  = acc0[4*g] + acc0[4*g+1] + acc0[4*g+2] + acc0[4*g+3]
                 + acc1[4*g] + acc1[4*g+1] + acc1[4*g+2] + acc1[4*g+3];
        float ss = acc0[4*g]*acc0[4*g] + acc0[4*g+1]*acc0[4*g+1]
                 + acc0[4*g+2]*acc0[4*g+2] + acc0[4*g+3]*acc0[4*g+3]
                 + acc1[4*g]*acc1[4*g] + acc1[4*g+1]*acc1[4*g+1]
                 + acc1[4*g+2]*acc1[4*g+2] + acc1[4*g+3]*acc1[4*g+3];
#pragma unroll
        for (int o = 4; o <= 32; o <<= 1) {
            s  += __shfl_xor(s,  o);
            ss += __shfl_xor(ss, o);
        }
        if ((t & 63) == 0) {
            atomicAdd(&lstat[g],      s);
            atomicAdd(&lstat[NG + g], ss);
        }
    }
    __syncthreads();
    if (t < 16) atomicAdd(&stats[t * 16], lstat[t]);   // padded: 1 counter/64B
}

// ---------------------------------------------------------------------------
// Kernel 3: GroupNorm finalize + affine + ReLU, IN-PLACE on d_out (float4)
// ---------------------------------------------------------------------------
__global__ __launch_bounds__(256) void k_gn(
    float* __restrict__ buf, const float* __restrict__ stats,
    const float* __restrict__ gamma, const float* __restrict__ beta)
{
    int idx  = blockIdx.x * 256 + threadIdx.x;   // float4 index
    int base = idx * 4;
    int ch = base / SP, g = ch >> 2;

    const float inv_n = 1.0f / (4.0f * (float)SP);
    float mean = stats[g * 16] * inv_n;
    float var  = stats[(NG + g) * 16] * inv_n - mean * mean;
    float rs   = rsqrtf(var + EPSV);
    float ga   = gamma[ch] * rs;
    float be   = beta[ch] - mean * ga;

    float4 p = *reinterpret_cast<const float4*>(buf + base);
    float4 o;
    o.x = fmaxf(p.x * ga + be, 0.0f);
    o.y = fmaxf(p.y * ga + be, 0.0f);
    o.z = fmaxf(p.z * ga + be, 0.0f);
    o.w = fmaxf(p.w * ga + be, 0.0f);
    *reinterpret_cast<float4*>(buf + base) = o;
}

// ---------------------------------------------------------------------------
extern "C" void kernel_launch(void* const* d_in, const int* in_sizes, int n_in,
                              void* d_out, int out_size, void* d_ws, size_t ws_size,
                              hipStream_t stream)
{
    const float* x   = (const float*)d_in[0];
    const float* ow  = (const float*)d_in[1];
    const float* ob  = (const float*)d_in[2];
    const float* bng = (const float*)d_in[3];
    const float* bnb = (const float*)d_in[4];
    const float* bnm = (const float*)d_in[5];
    const float* bnv = (const float*)d_in[6];
    const float* dw  = (const float*)d_in[7];
    const float* db  = (const float*)d_in[8];
    const float* gng = (const float*)d_in[9];
    const float* gnb = (const float*)d_in[10];
    float* out = (float*)d_out;

    float* xt    = (float*)d_ws;             // 16 * SP floats (7.08 MB)
    float* stats = xt + CIN * SP;            // 256 floats (padded counters)
    float* off   = stats + 256;              // 18 * SP floats (7.96 MB)

    k_xt   <<<SP / 64, 256, 0, stream>>>(x, xt, stats);
    k_off18<<<SP / 128, 256, 0, stream>>>(xt, ow, ob, bng, bnb, bnm, bnv, off);
    k_snake<<<SP / 64, 128, 0, stream>>>(xt, off, dw, db, out, stats);
    k_gn   <<<(COUT * SP / 4) / 256, 256, 0, stream>>>(out, stats, gng, gnb);
}